// Round 2
// baseline (525.287 us; speedup 1.0000x reference)
//
#include <hip/hip_runtime.h>
#include <hip/hip_bf16.h>
#include <math.h>

#define NN 131072
#define BSEG 16
#define CCH 128
#define KK 16
#define EPSF 1e-9f

// d_out layout (floats): out[B*K*C]=32768 | s[N*K]=2097152 | mu[B*K*2]=512 | losses[9]
#define OFF_S   32768
#define OFF_MU  2129920
#define OFF_L   2130432

// ws layout (floats): [0..255] sum_s[b*16+k] | [256..767] sum_s_pos[b*32+k*2+d] | [768] ent_sum | [769] batch-is-int64 flag

__device__ __forceinline__ int load_batch(const void* bptr, int n, int is64) {
    if (is64) return (int)((const long long*)bptr)[n];
    return ((const int*)bptr)[n];
}

__device__ __forceinline__ float wave_sum(float v) {
#pragma unroll
    for (int o = 32; o > 0; o >>= 1) v += __shfl_xor(v, o, 64);
    return v;
}

__global__ void k_detect(const int* __restrict__ b32, float* __restrict__ flag) {
    if (threadIdx.x == 0 && blockIdx.x == 0)
        flag[0] = (b32[NN - 1] == 0) ? 1.0f : 0.0f;  // int64 high word at odd idx => 0
}

__global__ void k_zero(float* __restrict__ out0, float* __restrict__ ws) {
    int i = blockIdx.x * 256 + threadIdx.x;
    if (i < BSEG * KK * CCH) out0[i] = 0.0f;
    if (i < 769) ws[i] = 0.0f;   // keep ws[769] (flag) intact
}

// One block = 128 nodes. 4 waves; wave w computes h/logit partials for j in [32w,32w+32)
// for ALL 128 nodes (2 nodes per lane). Then softmax + reductions + fused pooling.
__global__ __launch_bounds__(256, 2) void k_fused(
    const float* __restrict__ x, const void* __restrict__ batch,
    const float* __restrict__ pos, const float* __restrict__ gumbel,
    const float* __restrict__ W1, const float* __restrict__ b1,
    const float* __restrict__ W2, const float* __restrict__ b2,
    const float* __restrict__ scaling, const float* __restrict__ active_mask,
    float* __restrict__ s_out, float* __restrict__ out, float* __restrict__ ws)
{
    __shared__ float lgts[128 * 16];   // logits accum, later holds s
    __shared__ int   bsegs[128];

    const int tid = threadIdx.x;
    const int l   = tid & 63;          // lane
    const int wv  = tid >> 6;          // wave 0..3
    const int jb  = wv * 32;           // this wave's j-base
    const int n0  = blockIdx.x * 128;  // block node base
    const int is64 = (int)ws[769];

#pragma unroll
    for (int i = 0; i < 8; i++) lgts[tid * 8 + i] = 0.0f;
    if (tid < 128) bsegs[tid] = load_batch(batch, n0 + tid, is64);
    __syncthreads();

    // ---------------- phase 1: h = relu(x@W1^T + b1), j-slice per wave ----------------
    float acc0[32], acc1[32];
#pragma unroll
    for (int j = 0; j < 32; j++) { acc0[j] = 0.0f; acc1[j] = 0.0f; }

    const float* xrow0 = x + (size_t)(n0 + l) * CCH;
    const float* xrow1 = x + (size_t)(n0 + l + 64) * CCH;

    for (int ch = 0; ch < 4; ch++) {         // c-chunks of 32
        float4 xa[8], xb[8];
        const float4* pa = (const float4*)(xrow0 + ch * 32);
        const float4* pb = (const float4*)(xrow1 + ch * 32);
#pragma unroll
        for (int q = 0; q < 8; q++) { xa[q] = pa[q]; xb[q] = pb[q]; }

#pragma unroll 2
        for (int j = 0; j < 32; j++) {
            const float* wr = W1 + (size_t)(jb + j) * CCH + ch * 32;  // wave-uniform -> s_load
            float s0 = 0.f, s1 = 0.f;
#pragma unroll
            for (int q = 0; q < 8; q++) {
                s0 = fmaf(xa[q].x, wr[4 * q + 0], s0);
                s0 = fmaf(xa[q].y, wr[4 * q + 1], s0);
                s0 = fmaf(xa[q].z, wr[4 * q + 2], s0);
                s0 = fmaf(xa[q].w, wr[4 * q + 3], s0);
                s1 = fmaf(xb[q].x, wr[4 * q + 0], s1);
                s1 = fmaf(xb[q].y, wr[4 * q + 1], s1);
                s1 = fmaf(xb[q].z, wr[4 * q + 2], s1);
                s1 = fmaf(xb[q].w, wr[4 * q + 3], s1);
            }
            acc0[j] += s0; acc1[j] += s1;
        }
    }
#pragma unroll
    for (int j = 0; j < 32; j++) {
        const float bj = b1[jb + j];
        acc0[j] = fmaxf(acc0[j] + bj, 0.0f);
        acc1[j] = fmaxf(acc1[j] + bj, 0.0f);
    }

    // ---------------- phase 2: partial logits over this wave's j-slice ----------------
    float lg0[16], lg1[16];
#pragma unroll 2
    for (int k = 0; k < KK; k++) {
        const float* w2r = W2 + (size_t)k * CCH + jb;  // wave-uniform -> s_load
        float t0 = 0.f, t1 = 0.f;
#pragma unroll
        for (int j = 0; j < 32; j++) {
            t0 = fmaf(acc0[j], w2r[j], t0);
            t1 = fmaf(acc1[j], w2r[j], t1);
        }
        lg0[k] = t0; lg1[k] = t1;
    }
#pragma unroll
    for (int kk = 0; kk < KK; kk++) {
        int k = (kk + l) & 15;   // swizzle to spread LDS banks
        atomicAdd(&lgts[l * 16 + k], lg0[k]);
        atomicAdd(&lgts[(l + 64) * 16 + k], lg1[k]);
    }
    __syncthreads();

    // ---------------- phase 3: softmax + s write + segment reductions (waves 0,1) ----
    if (tid < 128) {
        const int n = n0 + tid;
        float lg[16];
#pragma unroll
        for (int i = 0; i < 4; i++) {
            float4 t = *(const float4*)&lgts[tid * 16 + 4 * i];
            lg[4 * i] = t.x; lg[4 * i + 1] = t.y; lg[4 * i + 2] = t.z; lg[4 * i + 3] = t.w;
        }
        float g[16];
        const float4* gv = (const float4*)(gumbel + (size_t)n * KK);
#pragma unroll
        for (int i = 0; i < 4; i++) {
            float4 t = gv[i];
            g[4 * i] = t.x; g[4 * i + 1] = t.y; g[4 * i + 2] = t.z; g[4 * i + 3] = t.w;
        }
        const float sc = scaling[0];
        float m = -1e30f;
#pragma unroll
        for (int k = 0; k < KK; k++) {
            float v = (lg[k] + b2[k]) * sc;
            if (active_mask[k] == 0.0f) v = -1e9f;
            v += g[k];                 // TAU == 1.0
            lg[k] = v;
            m = fmaxf(m, v);
        }
        float ssum = 0.0f;
#pragma unroll
        for (int k = 0; k < KK; k++) { lg[k] = expf(lg[k] - m); ssum += lg[k]; }
        const float inv = 1.0f / ssum;
        float sarr[16];
#pragma unroll
        for (int k = 0; k < KK; k++) sarr[k] = lg[k] * inv;

        float4* srow = (float4*)(s_out + (size_t)n * KK);
#pragma unroll
        for (int i = 0; i < 4; i++) {
            float4 t;
            t.x = sarr[4 * i]; t.y = sarr[4 * i + 1]; t.z = sarr[4 * i + 2]; t.w = sarr[4 * i + 3];
            *(float4*)&lgts[tid * 16 + 4 * i] = t;   // s into LDS for pool phase
            srow[i] = t;
        }

        float ent = 0.0f;
#pragma unroll
        for (int k = 0; k < KK; k++) ent += sarr[k] * logf(sarr[k] + EPSF);

        const float2 p = ((const float2*)pos)[n];
        const int lane = tid & 63;
        const int bi = bsegs[tid];
        const int b0 = __shfl(bi, 0, 64);
        const bool uni = (__all(bi == b0) != 0);
        if (uni) {
#pragma unroll
            for (int k = 0; k < KK; k++) {
                float v = wave_sum(sarr[k]);
                if (lane == 0) atomicAdd(&ws[b0 * KK + k], v);
            }
#pragma unroll
            for (int k = 0; k < KK; k++) {
                float vx = wave_sum(sarr[k] * p.x);
                float vy = wave_sum(sarr[k] * p.y);
                if (lane == 0) {
                    atomicAdd(&ws[256 + b0 * 32 + k * 2],     vx);
                    atomicAdd(&ws[256 + b0 * 32 + k * 2 + 1], vy);
                }
            }
            float e = wave_sum(ent);
            if (lane == 0) atomicAdd(&ws[768], e);
        } else {
#pragma unroll
            for (int k = 0; k < KK; k++) {
                atomicAdd(&ws[bi * KK + k], sarr[k]);
                atomicAdd(&ws[256 + bi * 32 + k * 2],     sarr[k] * p.x);
                atomicAdd(&ws[256 + bi * 32 + k * 2 + 1], sarr[k] * p.y);
            }
            atomicAdd(&ws[768], ent);
        }
    }
    __syncthreads();

    // ---------------- phase 4: fused pooling out[b,k,c] += s[n,k]*x[n,c] -------------
    {
        const int q  = tid >> 6;        // n-quarter (32 nodes)
        const int kg = (tid >> 5) & 1;  // k-group of 8
        const int cg = tid & 31;        // c-group of 4
        float racc[32];
#pragma unroll
        for (int i = 0; i < 32; i++) racc[i] = 0.0f;
        int curb = bsegs[q * 32];
        const float* xq = x + (size_t)n0 * CCH + cg * 4;

#pragma unroll 4
        for (int t = 0; t < 32; t++) {
            const int n = q * 32 + t;
            const int bn = bsegs[n];
            if (bn != curb) {
                float* ob = out + ((size_t)curb * KK + kg * 8) * CCH + cg * 4;
#pragma unroll
                for (int i = 0; i < 8; i++)
#pragma unroll
                    for (int jj = 0; jj < 4; jj++) {
                        atomicAdd(&ob[i * CCH + jj], racc[i * 4 + jj]);
                        racc[i * 4 + jj] = 0.0f;
                    }
                curb = bn;
            }
            float4 xv = *(const float4*)(xq + (size_t)n * CCH);
            float4 s0 = *(const float4*)&lgts[n * 16 + kg * 8];
            float4 s1 = *(const float4*)&lgts[n * 16 + kg * 8 + 4];
            float sv[8] = {s0.x, s0.y, s0.z, s0.w, s1.x, s1.y, s1.z, s1.w};
#pragma unroll
            for (int i = 0; i < 8; i++) {
                racc[i * 4 + 0] = fmaf(sv[i], xv.x, racc[i * 4 + 0]);
                racc[i * 4 + 1] = fmaf(sv[i], xv.y, racc[i * 4 + 1]);
                racc[i * 4 + 2] = fmaf(sv[i], xv.z, racc[i * 4 + 2]);
                racc[i * 4 + 3] = fmaf(sv[i], xv.w, racc[i * 4 + 3]);
            }
        }
        float* ob = out + ((size_t)curb * KK + kg * 8) * CCH + cg * 4;
#pragma unroll
        for (int i = 0; i < 8; i++)
#pragma unroll
            for (int jj = 0; jj < 4; jj++)
                atomicAdd(&ob[i * CCH + jj], racc[i * 4 + jj]);
    }
}

__global__ __launch_bounds__(256) void k_final(
    const float* __restrict__ ws, const float* __restrict__ active_mask,
    float* __restrict__ mu_out, float* __restrict__ losses)
{
    __shared__ float sums[256];
    __shared__ float smu[512];
    __shared__ float savg[16];
    __shared__ float red[256];
    const int tid = threadIdx.x;

    sums[tid] = ws[tid];
    __syncthreads();

    if (tid < 16) {
        float a = 0.0f;
#pragma unroll
        for (int b = 0; b < 16; b++) a += sums[b * 16 + tid];
        savg[tid] = a / (float)NN;
    }
    for (int i = tid; i < 512; i += 256) {
        int sk = i >> 1;   // b*16+k
        float v = ws[256 + i] / (sums[sk] + EPSF);
        smu[i] = v;
        mu_out[i] = v;
    }
    __syncthreads();

    float rep = 0.0f;
    for (int t = tid; t < 4096; t += 256) {
        int b = t >> 8, i = (t >> 4) & 15, j = t & 15;
        if (i != j) {
            float dx = smu[b * 32 + i * 2]     - smu[b * 32 + j * 2];
            float dy = smu[b * 32 + i * 2 + 1] - smu[b * 32 + j * 2 + 1];
            rep += 1.0f / (dx * dx + dy * dy + 1.0f);
        }
    }
    red[tid] = rep;
    __syncthreads();
    for (int st = 128; st > 0; st >>= 1) {
        if (tid < st) red[tid] += red[tid + st];
        __syncthreads();
    }

    if (tid == 0) {
        const float p = 1.0f / 16.0f;
        float separation = red[0] / (float)(16 * 15);
        float entropy = -ws[768] / (float)NN;
        float diversity = 0.f, pruning = 0.f, amsum = 0.f, collapse = 0.f, mean = 0.f;
        for (int k = 0; k < 16; k++) {
            float a = savg[k];
            diversity += p * logf(p / (a + EPSF));
            pruning += fabsf(a * (1.0f - active_mask[k]));
            amsum += active_mask[k];
            collapse += (a - p) * (a - p);
            mean += a;
        }
        pruning /= 16.0f;
        mean /= 16.0f;
        float var = 0.f;
        for (int k = 0; k < 16; k++) { float d = savg[k] - mean; var += d * d; }
        float balance = sqrtf(var / 16.0f);
        float sparsity = (amsum / 16.0f) * 0.01f;
        collapse *= 2.0f;
        losses[0] = entropy;   losses[1] = diversity; losses[2] = 0.0f;
        losses[3] = pruning;   losses[4] = sparsity;  losses[5] = 0.0f;
        losses[6] = collapse;  losses[7] = balance;   losses[8] = separation;
    }
}

extern "C" void kernel_launch(void* const* d_in, const int* in_sizes, int n_in,
                              void* d_out, int out_size, void* d_ws, size_t ws_size,
                              hipStream_t stream) {
    const float* x       = (const float*)d_in[0];
    const void*  batch   = d_in[1];
    const float* pos     = (const float*)d_in[2];
    const float* gumbel  = (const float*)d_in[3];
    const float* W1      = (const float*)d_in[4];
    const float* b1      = (const float*)d_in[5];
    const float* W2      = (const float*)d_in[6];
    const float* b2      = (const float*)d_in[7];
    const float* scaling = (const float*)d_in[8];
    const float* am      = (const float*)d_in[9];

    float* out      = (float*)d_out;
    float* s_sec    = out + OFF_S;
    float* mu_sec   = out + OFF_MU;
    float* loss_sec = out + OFF_L;
    float* wsf      = (float*)d_ws;

    k_detect<<<1, 64, 0, stream>>>((const int*)batch, wsf + 769);
    k_zero<<<128, 256, 0, stream>>>(out, wsf);
    k_fused<<<NN / 128, 256, 0, stream>>>(x, batch, pos, gumbel, W1, b1, W2, b2,
                                          scaling, am, s_sec, out, wsf);
    k_final<<<1, 256, 0, stream>>>(wsf, am, mu_sec, loss_sec);
}

// Round 3
// 286.431 us; speedup vs baseline: 1.8339x; 1.8339x over previous
//
#include <hip/hip_runtime.h>
#include <hip/hip_bf16.h>
#include <math.h>

#define NN 131072
#define BSEG 16
#define CCH 128
#define KK 16
#define EPSF 1e-9f
#define XST 136   // LDS row stride in bf16 elements (128 + 8 pad -> bank-staggered, 16B aligned)

// d_out layout (floats): out[B*K*C]=32768 | s[N*K]=2097152 | mu[B*K*2]=512 | losses[9]
#define OFF_S   32768
#define OFF_MU  2129920
#define OFF_L   2130432

// ws layout (floats): [0..255] sum_s[b*16+k] | [256..767] sum_s_pos[b*32+k*2+d] | [768] ent_sum | [769] is64 flag

typedef __bf16 bf16x8 __attribute__((ext_vector_type(8)));
typedef float  f32x4  __attribute__((ext_vector_type(4)));
typedef float  f32x16 __attribute__((ext_vector_type(16)));

__device__ __forceinline__ int load_batch(const void* bptr, int n, int is64) {
    if (is64) return (int)((const long long*)bptr)[n];
    return ((const int*)bptr)[n];
}

__device__ __forceinline__ float wave_sum(float v) {
#pragma unroll
    for (int o = 32; o > 0; o >>= 1) v += __shfl_xor(v, o, 64);
    return v;
}

__device__ __forceinline__ bf16x8 pack8(float4 a, float4 b) {
    bf16x8 v;
    v[0] = (__bf16)a.x; v[1] = (__bf16)a.y; v[2] = (__bf16)a.z; v[3] = (__bf16)a.w;
    v[4] = (__bf16)b.x; v[5] = (__bf16)b.y; v[6] = (__bf16)b.z; v[7] = (__bf16)b.w;
    return v;
}

__global__ void k_zero(float* __restrict__ out0, float* __restrict__ ws,
                       const int* __restrict__ b32) {
    int i = blockIdx.x * 256 + threadIdx.x;
    if (i < BSEG * KK * CCH) out0[i] = 0.0f;
    if (i < 769) ws[i] = 0.0f;
    if (i == 0) ws[769] = (b32[NN - 1] == 0) ? 1.0f : 0.0f;  // int64 high word at odd idx => 0
}

__global__ __launch_bounds__(256, 2) void k_fused(
    const float* __restrict__ x, const void* __restrict__ batch,
    const float* __restrict__ pos, const float* __restrict__ gumbel,
    const float* __restrict__ W1, const float* __restrict__ b1,
    const float* __restrict__ W2, const float* __restrict__ b2,
    const float* __restrict__ scaling, const float* __restrict__ active_mask,
    float* __restrict__ s_out, float* __restrict__ out, float* __restrict__ ws)
{
    __shared__ __align__(16) __bf16 x_lds[128 * XST];
    __shared__ __align__(16) __bf16 h_lds[128 * XST];  // row n: bytes [0,64) gumbel stash, [192,256) logits f32 (after h consumed)
    __shared__ __align__(16) __bf16 sT[16 * XST];
    __shared__ int bsegs[128];

    const int tid  = threadIdx.x;
    const int lane = tid & 63;
    const int wv   = tid >> 6;
    const int n0   = blockIdx.x * 128;
    const int is64 = (int)ws[769];

    // ---- prefetch gumbel (held in regs through the GEMMs) ----
    const float4* gptr = (const float4*)(gumbel + (size_t)n0 * KK) + tid * 2;
    float4 g0 = gptr[0], g1 = gptr[1];

    if (tid < 128) bsegs[tid] = load_batch(batch, n0 + tid, is64);

    // ---- stage x -> LDS bf16 ----
    {
        const float4* xg = (const float4*)(x + (size_t)n0 * CCH);
#pragma unroll
        for (int i = 0; i < 8; i++) {
            int p = i * 256 + tid;          // pair of float4 = 8 elements
            float4 a = xg[2 * p], b = xg[2 * p + 1];
            *(bf16x8*)&x_lds[(p >> 4) * XST + (p & 15) * 8] = pack8(a, b);
        }
    }
    __syncthreads();

    // ================= GEMM1: h = relu(x @ W1^T + b1), 32x32x16 =================
    // wave wv owns j-strip [32wv,32wv+32); computes all 4 node-tiles.
    {
        bf16x8 bfr[8];
        const float* wrow = W1 + (size_t)(wv * 32 + (lane & 31)) * CCH + (lane >> 5) * 8;
#pragma unroll
        for (int ks = 0; ks < 8; ks++) {
            float4 u = *(const float4*)(wrow + ks * 16);
            float4 v = *(const float4*)(wrow + ks * 16 + 4);
            bfr[ks] = pack8(u, v);
        }
        f32x16 acc[4];
#pragma unroll
        for (int mt = 0; mt < 4; mt++)
#pragma unroll
            for (int r = 0; r < 16; r++) acc[mt][r] = 0.0f;

#pragma unroll
        for (int ks = 0; ks < 8; ks++) {
#pragma unroll
            for (int mt = 0; mt < 4; mt++) {
                bf16x8 a = *(bf16x8*)&x_lds[(size_t)(mt * 32 + (lane & 31)) * XST + ks * 16 + (lane >> 5) * 8];
                acc[mt] = __builtin_amdgcn_mfma_f32_32x32x16_bf16(a, bfr[ks], acc[mt], 0, 0, 0);
            }
        }
        const float b1j = b1[wv * 32 + (lane & 31)];
#pragma unroll
        for (int mt = 0; mt < 4; mt++)
#pragma unroll
            for (int r = 0; r < 16; r++) {
                int node = mt * 32 + (r & 3) + 8 * (r >> 2) + 4 * (lane >> 5);
                h_lds[(size_t)node * XST + wv * 32 + (lane & 31)] = (__bf16)fmaxf(acc[mt][r] + b1j, 0.0f);
            }
    }
    __syncthreads();

    // ================= GEMM2: logits = h @ W2^T, 16x16x32 =================
    // wave wv owns node-tiles {2wv, 2wv+1} (rows [32wv,32wv+32) == the h rows it reads & logit rows it writes)
    {
        f32x4 acc2[2];
#pragma unroll
        for (int t = 0; t < 2; t++)
#pragma unroll
            for (int r = 0; r < 4; r++) acc2[t][r] = 0.0f;

#pragma unroll
        for (int ks = 0; ks < 4; ks++) {
            const float* w2row = W2 + (size_t)(lane & 15) * CCH + ks * 32 + (lane >> 4) * 8;
            float4 u = *(const float4*)w2row;
            float4 v = *(const float4*)(w2row + 4);
            bf16x8 bw = pack8(u, v);
#pragma unroll
            for (int t = 0; t < 2; t++) {
                int tile = wv * 2 + t;
                bf16x8 a = *(bf16x8*)&h_lds[(size_t)(tile * 16 + (lane & 15)) * XST + ks * 32 + (lane >> 4) * 8];
                acc2[t] = __builtin_amdgcn_mfma_f32_16x16x32_bf16(a, bw, acc2[t], 0, 0, 0);
            }
        }
        // write logits f32 into this wave's own (now dead) h rows, byte offset 192
#pragma unroll
        for (int t = 0; t < 2; t++) {
#pragma unroll
            for (int r = 0; r < 4; r++) {
                int node = (wv * 2 + t) * 16 + (lane >> 4) * 4 + r;
                float* lp = (float*)((char*)h_lds + (size_t)node * (XST * 2) + 192);
                lp[lane & 15] = acc2[t][r];
            }
        }
    }
    __syncthreads();

    // ---- stash gumbel regs into h rows, byte offset 0 ----
    {
        float* grow = (float*)((char*)h_lds + (size_t)(tid >> 1) * (XST * 2)) + (tid & 1) * 8;
        *(float4*)grow = g0;
        *(float4*)(grow + 4) = g1;
    }
    __syncthreads();

    // ================= softmax + s write + segment reductions (threads<128) =================
    if (tid < 128) {
        const int n = n0 + tid;
        const char* rb = (const char*)h_lds + (size_t)tid * (XST * 2);
        float lg[16], gu[16];
#pragma unroll
        for (int i = 0; i < 4; i++) {
            float4 t = *(const float4*)(rb + 192 + 16 * i);
            lg[4 * i] = t.x; lg[4 * i + 1] = t.y; lg[4 * i + 2] = t.z; lg[4 * i + 3] = t.w;
            float4 g = *(const float4*)(rb + 16 * i);
            gu[4 * i] = g.x; gu[4 * i + 1] = g.y; gu[4 * i + 2] = g.z; gu[4 * i + 3] = g.w;
        }
        const float sc = scaling[0];
        float m = -1e30f;
#pragma unroll
        for (int k = 0; k < KK; k++) {
            float v = (lg[k] + b2[k]) * sc;
            if (active_mask[k] == 0.0f) v = -1e9f;
            v += gu[k];                 // TAU == 1.0
            lg[k] = v;
            m = fmaxf(m, v);
        }
        float ssum = 0.0f;
#pragma unroll
        for (int k = 0; k < KK; k++) { lg[k] = expf(lg[k] - m); ssum += lg[k]; }
        const float inv = 1.0f / ssum;
        float sarr[16];
#pragma unroll
        for (int k = 0; k < KK; k++) sarr[k] = lg[k] * inv;

        float4* srow = (float4*)(s_out + (size_t)n * KK);
#pragma unroll
        for (int i = 0; i < 4; i++) {
            float4 t;
            t.x = sarr[4 * i]; t.y = sarr[4 * i + 1]; t.z = sarr[4 * i + 2]; t.w = sarr[4 * i + 3];
            srow[i] = t;
        }
#pragma unroll
        for (int k = 0; k < KK; k++) sT[k * XST + tid] = (__bf16)sarr[k];

        float ent = 0.0f;
#pragma unroll
        for (int k = 0; k < KK; k++) ent += sarr[k] * logf(sarr[k] + EPSF);

        const float2 p = ((const float2*)pos)[n];
        const int bi = bsegs[tid];
        const int b0 = __shfl(bi, 0, 64);
        const bool uni = (__all(bi == b0) != 0);
        if (uni) {
#pragma unroll
            for (int k = 0; k < KK; k++) {
                float v = wave_sum(sarr[k]);
                if (lane == 0) atomicAdd(&ws[b0 * KK + k], v);
            }
#pragma unroll
            for (int k = 0; k < KK; k++) {
                float vx = wave_sum(sarr[k] * p.x);
                float vy = wave_sum(sarr[k] * p.y);
                if (lane == 0) {
                    atomicAdd(&ws[256 + b0 * 32 + k * 2],     vx);
                    atomicAdd(&ws[256 + b0 * 32 + k * 2 + 1], vy);
                }
            }
            float e = wave_sum(ent);
            if (lane == 0) atomicAdd(&ws[768], e);
        } else {
#pragma unroll
            for (int k = 0; k < KK; k++) {
                atomicAdd(&ws[bi * KK + k], sarr[k]);
                atomicAdd(&ws[256 + bi * 32 + k * 2],     sarr[k] * p.x);
                atomicAdd(&ws[256 + bi * 32 + k * 2 + 1], sarr[k] * p.y);
            }
            atomicAdd(&ws[768], ent);
        }
    }
    __syncthreads();

    // ================= pooling: out[b,k,c] += s[n,k]*x[n,c] via 16x16x32 =================
    // D[m=ksup][n=c-tile], A = sT (b128), B = x (strided u16). wave owns c-tiles {2wv,2wv+1}.
    {
        const int bfirst = bsegs[0], blast = bsegs[127];
        for (int seg = bfirst; seg <= blast; seg++) {
            const bool masked = (bfirst != blast);
            f32x4 pacc[2];
#pragma unroll
            for (int t = 0; t < 2; t++)
#pragma unroll
                for (int r = 0; r < 4; r++) pacc[t][r] = 0.0f;

#pragma unroll
            for (int ks = 0; ks < 4; ks++) {
                bf16x8 a = *(bf16x8*)&sT[(size_t)(lane & 15) * XST + ks * 32 + (lane >> 4) * 8];
                if (masked) {
#pragma unroll
                    for (int i = 0; i < 8; i++) {
                        int nd = ks * 32 + (lane >> 4) * 8 + i;
                        if (bsegs[nd] != seg) a[i] = (__bf16)0.0f;
                    }
                }
#pragma unroll
                for (int t = 0; t < 2; t++) {
                    int ct = wv * 2 + t;
                    bf16x8 bx;
#pragma unroll
                    for (int i = 0; i < 8; i++)
                        bx[i] = x_lds[(size_t)(ks * 32 + (lane >> 4) * 8 + i) * XST + ct * 16 + (lane & 15)];
                    pacc[t] = __builtin_amdgcn_mfma_f32_16x16x32_bf16(a, bx, pacc[t], 0, 0, 0);
                }
            }
#pragma unroll
            for (int t = 0; t < 2; t++) {
                int c = (wv * 2 + t) * 16 + (lane & 15);
#pragma unroll
                for (int r = 0; r < 4; r++) {
                    int k = (lane >> 4) * 4 + r;
                    atomicAdd(&out[((size_t)seg * KK + k) * CCH + c], pacc[t][r]);
                }
            }
        }
    }
}

__global__ __launch_bounds__(256) void k_final(
    const float* __restrict__ ws, const float* __restrict__ active_mask,
    float* __restrict__ mu_out, float* __restrict__ losses)
{
    __shared__ float sums[256];
    __shared__ float smu[512];
    __shared__ float savg[16];
    __shared__ float red[256];
    const int tid = threadIdx.x;

    sums[tid] = ws[tid];
    __syncthreads();

    if (tid < 16) {
        float a = 0.0f;
#pragma unroll
        for (int b = 0; b < 16; b++) a += sums[b * 16 + tid];
        savg[tid] = a / (float)NN;
    }
    for (int i = tid; i < 512; i += 256) {
        int sk = i >> 1;   // b*16+k
        float v = ws[256 + i] / (sums[sk] + EPSF);
        smu[i] = v;
        mu_out[i] = v;
    }
    __syncthreads();

    float rep = 0.0f;
    for (int t = tid; t < 4096; t += 256) {
        int b = t >> 8, i = (t >> 4) & 15, j = t & 15;
        if (i != j) {
            float dx = smu[b * 32 + i * 2]     - smu[b * 32 + j * 2];
            float dy = smu[b * 32 + i * 2 + 1] - smu[b * 32 + j * 2 + 1];
            rep += 1.0f / (dx * dx + dy * dy + 1.0f);
        }
    }
    red[tid] = rep;
    __syncthreads();
    for (int st = 128; st > 0; st >>= 1) {
        if (tid < st) red[tid] += red[tid + st];
        __syncthreads();
    }

    if (tid == 0) {
        const float p = 1.0f / 16.0f;
        float separation = red[0] / (float)(16 * 15);
        float entropy = -ws[768] / (float)NN;
        float diversity = 0.f, pruning = 0.f, amsum = 0.f, collapse = 0.f, mean = 0.f;
        for (int k = 0; k < 16; k++) {
            float a = savg[k];
            diversity += p * logf(p / (a + EPSF));
            pruning += fabsf(a * (1.0f - active_mask[k]));
            amsum += active_mask[k];
            collapse += (a - p) * (a - p);
            mean += a;
        }
        pruning /= 16.0f;
        mean /= 16.0f;
        float var = 0.f;
        for (int k = 0; k < 16; k++) { float d = savg[k] - mean; var += d * d; }
        float balance = sqrtf(var / 16.0f);
        float sparsity = (amsum / 16.0f) * 0.01f;
        collapse *= 2.0f;
        losses[0] = entropy;   losses[1] = diversity; losses[2] = 0.0f;
        losses[3] = pruning;   losses[4] = sparsity;  losses[5] = 0.0f;
        losses[6] = collapse;  losses[7] = balance;   losses[8] = separation;
    }
}

extern "C" void kernel_launch(void* const* d_in, const int* in_sizes, int n_in,
                              void* d_out, int out_size, void* d_ws, size_t ws_size,
                              hipStream_t stream) {
    const float* x       = (const float*)d_in[0];
    const void*  batch   = d_in[1];
    const float* pos     = (const float*)d_in[2];
    const float* gumbel  = (const float*)d_in[3];
    const float* W1      = (const float*)d_in[4];
    const float* b1      = (const float*)d_in[5];
    const float* W2      = (const float*)d_in[6];
    const float* b2      = (const float*)d_in[7];
    const float* scaling = (const float*)d_in[8];
    const float* am      = (const float*)d_in[9];

    float* out      = (float*)d_out;
    float* s_sec    = out + OFF_S;
    float* mu_sec   = out + OFF_MU;
    float* loss_sec = out + OFF_L;
    float* wsf      = (float*)d_ws;

    k_zero<<<128, 256, 0, stream>>>(out, wsf, (const int*)batch);
    k_fused<<<NN / 128, 256, 0, stream>>>(x, batch, pos, gumbel, W1, b1, W2, b2,
                                          scaling, am, s_sec, out, wsf);
    k_final<<<1, 256, 0, stream>>>(wsf, am, mu_sec, loss_sec);
}